// Round 3
// baseline (238.786 us; speedup 1.0000x reference)
//
#include <hip/hip_runtime.h>
#include <math.h>

// Problem constants (from reference): T=128, B=4096, NOBS=32
#define T_DIM 128
#define B_DIM 4096
#define NOBS  32
#define LOG_2PI 1.8378770664093453f

constexpr int BLOCKS  = 2048;
constexpr int THREADS = 256;
constexpr int WAVES   = THREADS / 64;
constexpr int TOTAL_ELEMS = T_DIM * B_DIM * NOBS;   // 16,777,216 floats per tensor
constexpr int TOTAL4      = TOTAL_ELEMS / 4;        // 4,194,304 float4 per tensor
// TOTAL4 = BLOCKS*THREADS*8 exactly -> 8 float4 per thread per tensor.
constexpr int ITERS   = TOTAL4 / (BLOCKS * THREADS); // 8
static_assert(ITERS * BLOCKS * THREADS == TOTAL4, "exact tiling");

typedef float f32x4 __attribute__((ext_vector_type(4)));

#define GLOBAL_AS __attribute__((address_space(1)))
#define LDS_AS    __attribute__((address_space(3)))

__device__ __forceinline__ float softplus_f(float x) {
    // numerically-stable softplus: max(x,0) + log1p(exp(-|x|))
    return fmaxf(x, 0.0f) + log1pf(expf(-fabsf(x)));
}

// Direct global->LDS DMA, 16 B per lane, aux bit1 = nt (no L2/L3 allocation --
// keeps the Y stream from evicting Yhat lines; this Y-nt/Yhat-cached split is
// the best-measured configuration (R1: 152.3 us). R2's all-nt variant
// regressed (+3.7 us) -- cached Yhat loads are load-bearing.
__device__ __forceinline__ void dma_lds_16(const void* g, void* l) {
    __builtin_amdgcn_global_load_lds((const GLOBAL_AS void*)g,
                                     (LDS_AS void*)l, 16, 0, /*aux: nt*/ 2);
}

__global__ __launch_bounds__(THREADS) void elbo_fused_kernel(
    const float* __restrict__ Y,
    const float* __restrict__ Yhat,
    const float* __restrict__ raw_sn,
    const float* __restrict__ kl,
    const int*   __restrict__ Nptr,
    float* __restrict__ partial,
    unsigned int* __restrict__ ticket,   // zeroed by hipMemsetAsync pre-launch
    float* __restrict__ out)
{
    __shared__ f32x4 sh_y[ITERS * THREADS];   // 32 KB Y staging (R1 geometry)
    __shared__ float sh_sum[WAVES];
    __shared__ int   sh_last;

    const int tid  = threadIdx.x;
    const int wave = tid >> 6;   // wave-uniform
    const int lane = tid & 63;

    const int gtid = blockIdx.x * THREADS + tid;
    // float4 index i covers dims (4*i)%32 .. +3; grid stride is a multiple of
    // NOBS=32, so each thread's dim group is fixed.
    const int d0 = (gtid * 4) & (NOBS - 1);

    const f32x4* __restrict__ Y4 = (const f32x4*)Y;
    const f32x4* __restrict__ H4 = (const f32x4*)Yhat;
    constexpr int stride = BLOCKS * THREADS;

    // Issue ALL memory ops up front (16 bulk vector-mem instrs in flight/wave):
    //  - Y via global_load_lds DMA (nt, straight to LDS),
    //  - Yhat via plain cached loads into VGPRs.
    // LDS layout: chunk (m, wave) occupies 64 consecutive float4; HW places
    // lane i at chunk_base + i*16 -- exactly lane i's global element.
    // Chunk (m, wave) is written by wave `wave`'s OWN DMAs and read only by
    // that wave -> no cross-wave LDS dependency -> no barrier before compute.
    f32x4 h[ITERS];
    #pragma unroll
    for (int m = 0; m < ITERS; ++m) {
        dma_lds_16(&Y4[gtid + m * stride], &sh_y[(m * WAVES + wave) * 64]);
        h[m] = H4[gtid + m * stride];
    }

    // Per-thread inverse variances from one cached float4 load of raw_sn
    // (128 B array, broadcast). Overlaps the transcendentals with the bulk
    // memory wait.
    const f32x4 sn = *(const f32x4*)(raw_sn + d0);
    const float iv0 = 1.0f / softplus_f(sn.x);
    const float iv1 = 1.0f / softplus_f(sn.y);
    const float iv2 = 1.0f / softplus_f(sn.z);
    const float iv3 = 1.0f / softplus_f(sn.w);

    // 4 independent accumulators to break the FMA dependency chain.
    float a0 = 0.0f, a1 = 0.0f, a2 = 0.0f, a3 = 0.0f;

    // Progressive drain: before consuming chunk m, wait vmcnt(7-m).
    // Safety for ANY compiler interleave: pre-loop vmem ops <= 8 DMA + 9
    // non-DMA (8 h-loads + 1 sn-load); vmcnt retires in issue order, so after
    // s_waitcnt vmcnt(7-m) at least (17-(7-m)) - 9 = m+1 DMAs have completed,
    // i.e. chunk m is resident in LDS. The compiler's own waits for h[m]/sn
    // remain and only tighten; consumers below the asm are LDS reads, which
    // the "memory" clobber orders (no register-only-op hoist hazard).
    #define ELBO_STEP(M, NSTR) do {                                        \
        asm volatile("s_waitcnt vmcnt(" NSTR ")" ::: "memory");            \
        f32x4 y  = sh_y[((M) * WAVES + wave) * 64 + lane]; /* ds_read_b128 */ \
        f32x4 hh = h[(M)];                                                 \
        float d;                                                           \
        d = hh.x - y.x; a0 = fmaf(d * d, iv0, a0);                         \
        d = hh.y - y.y; a1 = fmaf(d * d, iv1, a1);                         \
        d = hh.z - y.z; a2 = fmaf(d * d, iv2, a2);                         \
        d = hh.w - y.w; a3 = fmaf(d * d, iv3, a3);                         \
    } while (0)

    ELBO_STEP(0, "7");
    ELBO_STEP(1, "6");
    ELBO_STEP(2, "5");
    ELBO_STEP(3, "4");
    ELBO_STEP(4, "3");
    ELBO_STEP(5, "2");
    ELBO_STEP(6, "1");
    ELBO_STEP(7, "0");
    #undef ELBO_STEP

    float acc = (a0 + a1) + (a2 + a3);

    // wave(64) shuffle reduction
    #pragma unroll
    for (int off = 32; off > 0; off >>= 1)
        acc += __shfl_down(acc, off, 64);

    if (lane == 0) sh_sum[wave] = acc;
    __syncthreads();

    // ---- fused finalization: last-block-done ticket ----
    if (tid == 0) {
        float s = 0.0f;
        #pragma unroll
        for (int w = 0; w < WAVES; ++w) s += sh_sum[w];
        partial[blockIdx.x] = s;
        __threadfence();                         // release: flush partial past
                                                 // the non-coherent per-XCD L2
        unsigned int old = atomicAdd(ticket, 1u); // device-scope RMW
        sh_last = (old == (unsigned int)(BLOCKS - 1));
    }
    __syncthreads();

    if (sh_last) {
        __threadfence();   // acquire side before reading other blocks' partials
        // 2048 partials / 256 threads = 8 scalar coherent loads each.
        // MUST be agent-scope loads: ws is re-poisoned every iteration, so this
        // XCD's L2 may hold stale poison lines for partial[] addresses.
        float facc = 0.0f;
        #pragma unroll
        for (int i = 0; i < BLOCKS / THREADS; ++i) {
            facc += __hip_atomic_load(&partial[i * THREADS + tid],
                                      __ATOMIC_RELAXED, __HIP_MEMORY_SCOPE_AGENT);
        }
        #pragma unroll
        for (int off = 32; off > 0; off >>= 1)
            facc += __shfl_down(facc, off, 64);

        if (lane == 0) sh_sum[wave] = facc;
        __syncthreads();
        if (tid == 0) {
            float S = (sh_sum[0] + sh_sum[1]) + (sh_sum[2] + sh_sum[3]);
            float logdet = 0.0f;
            #pragma unroll
            for (int d = 0; d < NOBS; ++d) {
                logdet += logf(softplus_f(raw_sn[d]));
            }
            // lhood = -0.5*N*(S/B + T*(logdet + NOBS*log2pi)); result = -lhood + kl
            float inner = S / (float)B_DIM
                        + (float)T_DIM * (logdet + (float)NOBS * LOG_2PI);
            out[0] = 0.5f * (float)(*Nptr) * inner + kl[0];
        }
    }
}

extern "C" void kernel_launch(void* const* d_in, const int* in_sizes, int n_in,
                              void* d_out, int out_size, void* d_ws, size_t ws_size,
                              hipStream_t stream) {
    const float* Y      = (const float*)d_in[0];
    const float* Yhat   = (const float*)d_in[1];
    const float* raw_sn = (const float*)d_in[2];
    const float* kl     = (const float*)d_in[3];
    const int*   N      = (const int*)d_in[4];
    float* partial        = (float*)d_ws;                       // 8 KB
    unsigned int* ticket  = (unsigned int*)((char*)d_ws + 8192); // 4 B, zeroed below
    float* out            = (float*)d_out;

    // Graph-capture-safe async 4-byte zero of the ticket (the harness itself
    // enqueues hipMemsetAsync during capture). ws is poisoned every iteration,
    // so the ticket must be re-zeroed every call.
    hipMemsetAsync(ticket, 0, sizeof(unsigned int), stream);

    elbo_fused_kernel<<<BLOCKS, THREADS, 0, stream>>>(
        Y, Yhat, raw_sn, kl, N, partial, ticket, out);
}

// Round 4
// 151.491 us; speedup vs baseline: 1.5762x; 1.5762x over previous
//
#include <hip/hip_runtime.h>
#include <math.h>

// Problem constants (from reference): T=128, B=4096, NOBS=32
#define T_DIM 128
#define B_DIM 4096
#define NOBS  32
#define LOG_2PI 1.8378770664093453f

constexpr int BLOCKS  = 2048;
constexpr int THREADS = 256;
constexpr int WAVES   = THREADS / 64;
constexpr int TOTAL_ELEMS = T_DIM * B_DIM * NOBS;   // 16,777,216 floats per tensor
constexpr int TOTAL4      = TOTAL_ELEMS / 4;        // 4,194,304 float4 per tensor
// TOTAL4 = BLOCKS*THREADS*8 exactly -> 8 float4 per thread per tensor.
constexpr int ITERS   = TOTAL4 / (BLOCKS * THREADS); // 8
static_assert(ITERS * BLOCKS * THREADS == TOTAL4, "exact tiling");

typedef float f32x4 __attribute__((ext_vector_type(4)));

#define GLOBAL_AS __attribute__((address_space(1)))
#define LDS_AS    __attribute__((address_space(3)))

// ---------------------------------------------------------------------------
// SESSION LEDGER (measured on MI355X):
//   R0 baseline (barrier + sh_iv):                     153.6 us
//   R1 = THIS KERNEL (no barrier, counted vmcnt):      152.3 us  <- best
//   R2 (all-nt + 4096x4 geometry + slim final):        156.1 us  REGRESSED
//   R3 (single-kernel fusion w/ __threadfence ticket): 238.8 us  REGRESSED
// R3 mechanism: per-block device-scope __threadfence on gfx950 = whole-L2
// writeback/invalidate; 2048 staggered finishers thrash every XCD's L2 while
// siblings still stream -> 455 GB/s effective. Do NOT fuse with fences here.
// This file is the exact R1 revert.
// ---------------------------------------------------------------------------

__device__ __forceinline__ float softplus_f(float x) {
    // numerically-stable softplus: max(x,0) + log1p(exp(-|x|))
    return fmaxf(x, 0.0f) + log1pf(expf(-fabsf(x)));
}

// Direct global->LDS DMA, 16 B per lane, aux bit1 = nt (no L2/L3 allocation --
// keeps the Y stream from evicting Yhat lines; the Y-nt/Yhat-cached split is
// the best-measured configuration. R2's all-nt variant regressed +3.7 us:
// cached Yhat loads are load-bearing.)
__device__ __forceinline__ void dma_lds_16(const void* g, void* l) {
    __builtin_amdgcn_global_load_lds((const GLOBAL_AS void*)g,
                                     (LDS_AS void*)l, 16, 0, /*aux: nt*/ 2);
}

__global__ __launch_bounds__(THREADS) void elbo_partial_kernel(
    const float* __restrict__ Y,
    const float* __restrict__ Yhat,
    const float* __restrict__ raw_sn,
    float* __restrict__ partial)
{
    __shared__ f32x4 sh_y[ITERS * THREADS];   // 32 KB Y staging
    __shared__ float sh_sum[WAVES];

    const int tid  = threadIdx.x;
    const int wave = tid >> 6;   // wave-uniform
    const int lane = tid & 63;

    const int gtid = blockIdx.x * THREADS + tid;
    // float4 index i covers dims (4*i)%32 .. +3; grid stride is a multiple of
    // NOBS=32, so each thread's dim group is fixed.
    const int d0 = (gtid * 4) & (NOBS - 1);

    const f32x4* __restrict__ Y4 = (const f32x4*)Y;
    const f32x4* __restrict__ H4 = (const f32x4*)Yhat;
    constexpr int stride = BLOCKS * THREADS;

    // Issue ALL memory ops up front (16 bulk vector-mem instrs in flight/wave):
    //  - Y via global_load_lds DMA (nt, straight to LDS),
    //  - Yhat via plain cached loads into VGPRs.
    // LDS layout: chunk (m, wave) occupies 64 consecutive float4; HW places
    // lane i at chunk_base + i*16 -- exactly lane i's global element.
    // Chunk (m, wave) is written by wave `wave`'s OWN DMAs and read only by
    // that wave -> no cross-wave LDS dependency -> no barrier before compute.
    f32x4 h[ITERS];
    #pragma unroll
    for (int m = 0; m < ITERS; ++m) {
        dma_lds_16(&Y4[gtid + m * stride], &sh_y[(m * WAVES + wave) * 64]);
        h[m] = H4[gtid + m * stride];
    }

    // Per-thread inverse variances from one cached float4 load of raw_sn
    // (128 B array, broadcast). Overlaps the transcendentals with the bulk
    // memory wait.
    const f32x4 sn = *(const f32x4*)(raw_sn + d0);
    const float iv0 = 1.0f / softplus_f(sn.x);
    const float iv1 = 1.0f / softplus_f(sn.y);
    const float iv2 = 1.0f / softplus_f(sn.z);
    const float iv3 = 1.0f / softplus_f(sn.w);

    // 4 independent accumulators to break the FMA dependency chain.
    float a0 = 0.0f, a1 = 0.0f, a2 = 0.0f, a3 = 0.0f;

    // Progressive drain: before consuming chunk m, wait vmcnt(7-m).
    // Safety for ANY compiler interleave: pre-loop vmem ops <= 8 DMA + 9
    // non-DMA (8 h-loads + 1 sn-load); vmcnt retires in issue order, so after
    // s_waitcnt vmcnt(7-m) at least (17-(7-m)) - 9 = m+1 DMAs have completed,
    // i.e. chunk m is resident in LDS. The compiler's own waits for h[m]/sn
    // remain and only tighten; consumers below the asm are LDS reads, which
    // the "memory" clobber orders (no register-only-op hoist hazard).
    #define ELBO_STEP(M, NSTR) do {                                        \
        asm volatile("s_waitcnt vmcnt(" NSTR ")" ::: "memory");            \
        f32x4 y  = sh_y[((M) * WAVES + wave) * 64 + lane]; /* ds_read_b128 */ \
        f32x4 hh = h[(M)];                                                 \
        float d;                                                           \
        d = hh.x - y.x; a0 = fmaf(d * d, iv0, a0);                         \
        d = hh.y - y.y; a1 = fmaf(d * d, iv1, a1);                         \
        d = hh.z - y.z; a2 = fmaf(d * d, iv2, a2);                         \
        d = hh.w - y.w; a3 = fmaf(d * d, iv3, a3);                         \
    } while (0)

    ELBO_STEP(0, "7");
    ELBO_STEP(1, "6");
    ELBO_STEP(2, "5");
    ELBO_STEP(3, "4");
    ELBO_STEP(4, "3");
    ELBO_STEP(5, "2");
    ELBO_STEP(6, "1");
    ELBO_STEP(7, "0");
    #undef ELBO_STEP

    float acc = (a0 + a1) + (a2 + a3);

    // wave(64) shuffle reduction
    #pragma unroll
    for (int off = 32; off > 0; off >>= 1)
        acc += __shfl_down(acc, off, 64);

    if (lane == 0) sh_sum[wave] = acc;
    __syncthreads();   // only barrier in the kernel: cross-wave sum exchange
    if (tid == 0) {
        float s = 0.0f;
        #pragma unroll
        for (int w = 0; w < WAVES; ++w) s += sh_sum[w];
        partial[blockIdx.x] = s;
    }
}

__global__ __launch_bounds__(256) void elbo_final_kernel(
    const float* __restrict__ partial,
    const float* __restrict__ raw_sn,
    const float* __restrict__ kl,
    const int*   __restrict__ Nptr,
    float* __restrict__ out)
{
    const int tid = threadIdx.x;
    float acc = 0.0f;
    for (int i = tid; i < BLOCKS; i += 256) acc += partial[i];

    #pragma unroll
    for (int off = 32; off > 0; off >>= 1)
        acc += __shfl_down(acc, off, 64);

    __shared__ float sh[4];
    if ((tid & 63) == 0) sh[tid >> 6] = acc;
    __syncthreads();

    if (tid == 0) {
        float S = sh[0] + sh[1] + sh[2] + sh[3];
        float logdet = 0.0f;
        #pragma unroll
        for (int d = 0; d < NOBS; ++d) {
            logdet += logf(softplus_f(raw_sn[d]));
        }
        // lhood = -0.5*N*(S/B + T*(logdet + NOBS*log2pi)); result = -lhood + kl
        float inner = S / (float)B_DIM + (float)T_DIM * (logdet + (float)NOBS * LOG_2PI);
        out[0] = 0.5f * (float)(*Nptr) * inner + kl[0];
    }
}

extern "C" void kernel_launch(void* const* d_in, const int* in_sizes, int n_in,
                              void* d_out, int out_size, void* d_ws, size_t ws_size,
                              hipStream_t stream) {
    const float* Y      = (const float*)d_in[0];
    const float* Yhat   = (const float*)d_in[1];
    const float* raw_sn = (const float*)d_in[2];
    const float* kl     = (const float*)d_in[3];
    const int*   N      = (const int*)d_in[4];
    float* partial = (float*)d_ws;   // BLOCKS floats = 8 KB scratch (overwritten every call)
    float* out     = (float*)d_out;

    elbo_partial_kernel<<<BLOCKS, THREADS, 0, stream>>>(Y, Yhat, raw_sn, partial);
    elbo_final_kernel<<<1, 256, 0, stream>>>(partial, raw_sn, kl, N, out);
}